// Round 1
// baseline (54992.352 us; speedup 1.0000x reference)
//
#include <hip/hip_runtime.h>
#include <cstddef>

namespace {

constexpr int Hd = 512;   // hidden
constexpr int Bd = 256;   // batch
constexpr int Td = 512;   // seq len

__device__ __forceinline__ float sigm(float z) {
    return 1.0f / (1.0f + __expf(-z));
}
__device__ __forceinline__ float tanh_fast(float z) {
    // 1 - 2/(1+e^{2z}) ; saturates correctly at +/-1
    return 1.0f - 2.0f / (1.0f + __expf(2.0f * z));
}

// One LSTM time step:
//   gates = h_in @ W^T + x_t * Wih + bih + bhh   (rows: [i(512) f g o])
//   c = sig(f)*c + sig(i)*tanh(g);  h_out = sig(o)*tanh(c)
// Grid: 256 blocks = 8 batch-groups x 32 j-groups. Block: 256 threads.
// Thread: 2 batches x 1 hidden-elem x 4 gates (8 dot products of K=512).
// h double-buffered across launches (read h_in, write h_out) to avoid the
// read-while-write race between j-slices of the same batch.
__global__ __launch_bounds__(256) void lstm_step(
    const float* __restrict__ W,     // [4H, H] row-major
    const float* __restrict__ Wih,   // [4H]
    const float* __restrict__ bih,   // [4H]
    const float* __restrict__ bhh,   // [4H]
    const float* __restrict__ x,     // [B, T]
    int t,
    const float* __restrict__ h_in,  // [B, H]
    float* __restrict__ h_out,       // [B, H]
    float* __restrict__ c,           // [B, H] (owner-only, in-place)
    const float* __restrict__ linW,  // [H]
    const float* __restrict__ linb,  // [1]
    float* __restrict__ out,         // [B, T] or unused
    int is_dec)
{
    const int tid = threadIdx.x;
    const int bp  = tid & 15;          // batch-pair 0..15
    const int jl  = tid >> 4;          // 0..15
    const int jg  = blockIdx.x & 31;   // j-group 0..31
    const int bg  = blockIdx.x >> 5;   // batch-group 0..7
    const int j   = jg * 16 + jl;      // hidden index 0..511
    const int b0  = bg * 32 + bp * 2;
    const int b1  = b0 + 1;

    const float x0 = x[(size_t)b0 * Td + t];
    const float x1 = x[(size_t)b1 * Td + t];

    float acc0[4], acc1[4];
    const float4* wrow[4];
#pragma unroll
    for (int q = 0; q < 4; ++q) {
        const int r = q * Hd + j;
        const float bias = bih[r] + bhh[r];
        const float wx = Wih[r];
        acc0[q] = bias + x0 * wx;
        acc1[q] = bias + x1 * wx;
        wrow[q] = reinterpret_cast<const float4*>(W + (size_t)r * Hd);
    }

    const float4* h0p = reinterpret_cast<const float4*>(h_in + (size_t)b0 * Hd);
    const float4* h1p = reinterpret_cast<const float4*>(h_in + (size_t)b1 * Hd);

#pragma unroll 4
    for (int k4 = 0; k4 < Hd / 4; ++k4) {
        const float4 ha = h0p[k4];
        const float4 hb = h1p[k4];
#pragma unroll
        for (int q = 0; q < 4; ++q) {
            const float4 w = wrow[q][k4];
            acc0[q] += w.x * ha.x + w.y * ha.y + w.z * ha.z + w.w * ha.w;
            acc1[q] += w.x * hb.x + w.y * hb.y + w.z * hb.z + w.w * hb.w;
        }
    }

    // cell update for both batches
    const float lw = linW[j];
    float p0, p1;
    {
        const float ig = sigm(acc0[0]);
        const float fg = sigm(acc0[1]);
        const float gg = tanh_fast(acc0[2]);
        const float og = sigm(acc0[3]);
        const size_t ci = (size_t)b0 * Hd + j;
        const float cn = fg * c[ci] + ig * gg;
        c[ci] = cn;
        const float hn = og * tanh_fast(cn);
        h_out[ci] = hn;
        p0 = hn * lw;
    }
    {
        const float ig = sigm(acc1[0]);
        const float fg = sigm(acc1[1]);
        const float gg = tanh_fast(acc1[2]);
        const float og = sigm(acc1[3]);
        const size_t ci = (size_t)b1 * Hd + j;
        const float cn = fg * c[ci] + ig * gg;
        c[ci] = cn;
        const float hn = og * tanh_fast(cn);
        h_out[ci] = hn;
        p1 = hn * lw;
    }

    if (is_dec) {
        // reduce partials over the 16 j's of this block, one atomic per batch
        __shared__ float part[16][34];
        part[jl][bp * 2]     = p0;
        part[jl][bp * 2 + 1] = p1;
        __syncthreads();
        if (tid < 32) {
            float s = 0.0f;
#pragma unroll
            for (int r = 0; r < 16; ++r) s += part[r][tid];
            if (jg == 0) s += linb[0];
            atomicAdd(&out[(size_t)(bg * 32 + tid) * Td + t], s);
        }
    }
}

} // namespace

extern "C" void kernel_launch(void* const* d_in, const int* in_sizes, int n_in,
                              void* d_out, int out_size, void* d_ws, size_t ws_size,
                              hipStream_t stream) {
    const float* x    = (const float*)d_in[0];
    const float* eWih = (const float*)d_in[1];
    const float* eWhh = (const float*)d_in[2];
    const float* ebih = (const float*)d_in[3];
    const float* ebhh = (const float*)d_in[4];
    const float* dWih = (const float*)d_in[5];
    const float* dWhh = (const float*)d_in[6];
    const float* dbih = (const float*)d_in[7];
    const float* dbhh = (const float*)d_in[8];
    const float* linW = (const float*)d_in[9];
    const float* linb = (const float*)d_in[10];
    float* out = (float*)d_out;

    float* hA = (float*)d_ws;
    float* hB = hA + (size_t)Bd * Hd;
    float* c  = hB + (size_t)Bd * Hd;

    // zero h (initial state), c, and the atomically-accumulated output
    hipMemsetAsync(d_ws, 0, 3 * (size_t)Bd * Hd * sizeof(float), stream);
    hipMemsetAsync(d_out, 0, (size_t)out_size * sizeof(float), stream);

    dim3 grid(256), block(256);
    float* hin = hA;
    float* hout = hB;

    for (int t = 0; t < Td; ++t) {
        lstm_step<<<grid, block, 0, stream>>>(eWhh, eWih, ebih, ebhh, x, t,
                                              hin, hout, c, linW, linb,
                                              nullptr, 0);
        float* tmp = hin; hin = hout; hout = tmp;
    }

    // decoder: h carries over (hT), c resets to zero
    hipMemsetAsync(c, 0, (size_t)Bd * Hd * sizeof(float), stream);

    for (int t = 0; t < Td; ++t) {
        lstm_step<<<grid, block, 0, stream>>>(dWhh, dWih, dbih, dbhh, x, t,
                                              hin, hout, c, linW, linb,
                                              out, 1);
        float* tmp = hin; hin = hout; hout = tmp;
    }
}

// Round 2
// 19847.617 us; speedup vs baseline: 2.7707x; 2.7707x over previous
//
#include <hip/hip_runtime.h>
#include <cstddef>

namespace {

constexpr int Hd = 512;   // hidden
constexpr int Bd = 256;   // batch
constexpr int Td = 512;   // seq len

__device__ __forceinline__ float sigm(float z) {
    return 1.0f / (1.0f + __expf(-z));
}
__device__ __forceinline__ float tanh_fast(float z) {
    return 1.0f - 2.0f / (1.0f + __expf(2.0f * z));
}
__device__ __forceinline__ float dot4(float acc, float4 w, float4 h) {
    acc = fmaf(w.x, h.x, acc);
    acc = fmaf(w.y, h.y, acc);
    acc = fmaf(w.z, h.z, acc);
    acc = fmaf(w.w, h.w, acc);
    return acc;
}

// One LSTM step. Block tile: 32 virtual rows (8 j's x 4 gates, v = j*4+gate)
// x 32 batches. Grid: 512 = 8 bg x 64 rg (bid = bg*64+rg so blocks sharing a
// W-slice land on one XCD). Threads 256: tid = rp(16) + 16*bp(16); thread
// owns rows {2rp,2rp+1} x batches {2bp,2bp+1}. K processed in 4 double-
// buffered LDS tiles of 128. W tile XOR-swizzled (slot = j ^ ((r>>1)&7)),
// h tile padded to 33 float4/row; h reads are 16-lane broadcasts.
__global__ __launch_bounds__(256, 2) void lstm_step(
    const float* __restrict__ W,     // [4H, H] row-major (torch i,f,g,o)
    const float* __restrict__ Wih,   // [4H]
    const float* __restrict__ bih,   // [4H]
    const float* __restrict__ bhh,   // [4H]
    const float* __restrict__ x,     // [B, T]
    int t,
    const float* __restrict__ h_in,  // [B, H]
    float* __restrict__ h_out,       // [B, H]
    float* __restrict__ c,           // [B, H] in-place (owner-only)
    const float* __restrict__ linW,  // [H]
    const float* __restrict__ linb,  // [1]
    float* __restrict__ out,         // [B, T] (decoder) or unused
    int is_dec)
{
    __shared__ float4 Wb[2][32][32];      // 32 KB, XOR-swizzled slots
    __shared__ float4 Hb[2][32 * 33];     // 33 KB, padded rows (33 f4)

    const int tid = threadIdx.x;
    const int rp  = tid & 15;
    const int bp  = tid >> 4;
    const int rg  = blockIdx.x & 63;     // row-group 0..63
    const int bg  = blockIdx.x >> 6;     // batch-group 0..7

    // this thread's two virtual rows -> source rows in W / bias arrays
    const int v0 = rg * 32 + 2 * rp;
    const int v1 = v0 + 1;
    const int s0 = (v0 & 3) * Hd + (v0 >> 2);
    const int s1 = (v1 & 3) * Hd + (v1 >> 2);
    const int b0 = bg * 32 + 2 * bp;
    const int b1 = b0 + 1;

    const float x0 = x[(size_t)b0 * Td + t];
    const float x1 = x[(size_t)b1 * Td + t];
    const float bias0 = bih[s0] + bhh[s0];
    const float bias1 = bih[s1] + bhh[s1];
    const float wx0 = Wih[s0];
    const float wx1 = Wih[s1];

    float a00 = bias0 + x0 * wx0;   // (row v0, b0)
    float a01 = bias0 + x1 * wx0;   // (row v0, b1)
    float a10 = bias1 + x0 * wx1;   // (row v1, b0)
    float a11 = bias1 + x1 * wx1;   // (row v1, b1)

    const float4* Wg = reinterpret_cast<const float4*>(W);     // [4H][128]
    const float4* Hg = reinterpret_cast<const float4*>(h_in);  // [B][128]

    // staging decomposition: chunk p covers q = p*256+tid; r = q>>5 (row /
    // local batch), jj = q&31 (f4 column within the k-tile)
    int sr[4], sjj[4], swslot[4], srcrow[4], sbat[4];
#pragma unroll
    for (int p = 0; p < 4; ++p) {
        const int q = p * 256 + tid;
        const int r = q >> 5, jj = q & 31;
        sr[p] = r; sjj[p] = jj;
        swslot[p] = jj ^ ((r >> 1) & 7);
        const int v = rg * 32 + r;
        srcrow[p] = (v & 3) * Hd + (v >> 2);
        sbat[p] = bg * 32 + r;
    }

    float4 rW[4], rH[4];
    // prologue: stage k-tile 0
#pragma unroll
    for (int p = 0; p < 4; ++p) {
        rW[p] = Wg[(size_t)srcrow[p] * 128 + sjj[p]];
        rH[p] = Hg[(size_t)sbat[p] * 128 + sjj[p]];
    }
#pragma unroll
    for (int p = 0; p < 4; ++p) {
        Wb[0][sr[p]][swslot[p]] = rW[p];
        Hb[0][sr[p] * 33 + sjj[p]] = rH[p];
    }
    __syncthreads();

    const int key = rp & 7;
    const int wr0 = 2 * rp;
    const int hb0 = (2 * bp) * 33;

#pragma unroll
    for (int kt = 0; kt < 4; ++kt) {
        const int cur = kt & 1;
        const int nxt = cur ^ 1;
        if (kt < 3) {
#pragma unroll
            for (int p = 0; p < 4; ++p) {
                rW[p] = Wg[(size_t)srcrow[p] * 128 + (kt + 1) * 32 + sjj[p]];
                rH[p] = Hg[(size_t)sbat[p] * 128 + (kt + 1) * 32 + sjj[p]];
            }
        }
#pragma unroll 8
        for (int j = 0; j < 32; ++j) {
            const int js = j ^ key;
            const float4 w0 = Wb[cur][wr0][js];
            const float4 w1 = Wb[cur][wr0 + 1][js];
            const float4 h0 = Hb[cur][hb0 + j];
            const float4 h1 = Hb[cur][hb0 + 33 + j];
            a00 = dot4(a00, w0, h0);
            a01 = dot4(a01, w0, h1);
            a10 = dot4(a10, w1, h0);
            a11 = dot4(a11, w1, h1);
        }
        if (kt < 3) {
#pragma unroll
            for (int p = 0; p < 4; ++p) {
                Wb[nxt][sr[p]][swslot[p]] = rW[p];
                Hb[nxt][sr[p] * 33 + sjj[p]] = rH[p];
            }
        }
        __syncthreads();
    }

    // --- epilogue ---
    // even rp: rows = (i,f) of j = rg*8 + rp/2; odd rp: rows = (g,o) of same j
    const float g0 = __shfl_xor(a00, 1);   // even lane receives g-preact (b0)
    const float g1 = __shfl_xor(a01, 1);   // (b1)
    const float o0 = __shfl_xor(a10, 1);   // o-preact (b0)
    const float o1 = __shfl_xor(a11, 1);   // (b1)

    float p0 = 0.0f, p1 = 0.0f;
    if ((rp & 1) == 0) {
        const int j = rg * 8 + (rp >> 1);
        const float lw = is_dec ? linW[j] : 0.0f;
        {
            const size_t ci = (size_t)b0 * Hd + j;
            const float cn = sigm(a10) * c[ci] + sigm(a00) * tanh_fast(g0);
            c[ci] = cn;
            const float hn = sigm(o0) * tanh_fast(cn);
            h_out[ci] = hn;
            p0 = hn * lw;
        }
        {
            const size_t ci = (size_t)b1 * Hd + j;
            const float cn = sigm(a11) * c[ci] + sigm(a01) * tanh_fast(g1);
            c[ci] = cn;
            const float hn = sigm(o1) * tanh_fast(cn);
            h_out[ci] = hn;
            p1 = hn * lw;
        }
    }

    if (is_dec) {
        // reduce the 8 j-partials of this block's 16-lane group
        p0 += __shfl_xor(p0, 2);  p1 += __shfl_xor(p1, 2);
        p0 += __shfl_xor(p0, 4);  p1 += __shfl_xor(p1, 4);
        p0 += __shfl_xor(p0, 8);  p1 += __shfl_xor(p1, 8);
        if (rp == 0) {
            const float bias = (rg == 0) ? linb[0] : 0.0f;
            atomicAdd(&out[(size_t)b0 * Td + t], p0 + bias);
            atomicAdd(&out[(size_t)b1 * Td + t], p1 + bias);
        }
    }
}

} // namespace

extern "C" void kernel_launch(void* const* d_in, const int* in_sizes, int n_in,
                              void* d_out, int out_size, void* d_ws, size_t ws_size,
                              hipStream_t stream) {
    (void)in_sizes; (void)n_in; (void)ws_size;
    const float* x    = (const float*)d_in[0];
    const float* eWih = (const float*)d_in[1];
    const float* eWhh = (const float*)d_in[2];
    const float* ebih = (const float*)d_in[3];
    const float* ebhh = (const float*)d_in[4];
    const float* dWih = (const float*)d_in[5];
    const float* dWhh = (const float*)d_in[6];
    const float* dbih = (const float*)d_in[7];
    const float* dbhh = (const float*)d_in[8];
    const float* linW = (const float*)d_in[9];
    const float* linb = (const float*)d_in[10];
    float* out = (float*)d_out;

    float* hA = (float*)d_ws;
    float* hB = hA + (size_t)Bd * Hd;
    float* c  = hB + (size_t)Bd * Hd;

    hipMemsetAsync(d_ws, 0, 3 * (size_t)Bd * Hd * sizeof(float), stream);
    hipMemsetAsync(d_out, 0, (size_t)out_size * sizeof(float), stream);

    dim3 grid(512), block(256);
    float* hin = hA;
    float* hout = hB;

    for (int t = 0; t < Td; ++t) {
        lstm_step<<<grid, block, 0, stream>>>(eWhh, eWih, ebih, ebhh, x, t,
                                              hin, hout, c, linW, linb,
                                              nullptr, 0);
        float* tmp = hin; hin = hout; hout = tmp;
    }

    hipMemsetAsync(c, 0, (size_t)Bd * Hd * sizeof(float), stream);

    for (int t = 0; t < Td; ++t) {
        lstm_step<<<grid, block, 0, stream>>>(dWhh, dWih, dbih, dbhh, x, t,
                                              hin, hout, c, linW, linb,
                                              out, 1);
        float* tmp = hin; hin = hout; hout = tmp;
    }
}

// Round 3
// 9733.044 us; speedup vs baseline: 5.6501x; 2.0392x over previous
//
#include <hip/hip_runtime.h>
#include <cstddef>
#include <cstdint>

namespace {

constexpr int Hd = 512;   // hidden
constexpr int Bd = 256;   // batch
constexpr int Td = 512;   // seq len
constexpr int Vd = 2048;  // 4*H gate rows

typedef _Float16 f16x8 __attribute__((ext_vector_type(8)));
typedef float f32x4 __attribute__((ext_vector_type(4)));

__device__ __forceinline__ float sigm(float z) { return 1.0f / (1.0f + __expf(-z)); }
__device__ __forceinline__ float tanh_fast(float z) {
    return 1.0f - 2.0f / (1.0f + __expf(2.0f * z));
}

__device__ __forceinline__ void gl2lds16(const _Float16* g, _Float16* l) {
    __builtin_amdgcn_global_load_lds(
        (const __attribute__((address_space(1))) uint32_t*)(const void*)g,
        (__attribute__((address_space(3))) uint32_t*)(void*)l,
        16, 0, 0);
}

// Split W[4H,H] (torch row s = q*H + j) into fp16 hi/lo with row permutation
// v = 4*j + q; also fold biases bb[v] = bih+bhh and wx[v] = Wih.
__global__ __launch_bounds__(256) void prep_weights(
    const float* __restrict__ Wsrc, const float* __restrict__ bih,
    const float* __restrict__ bhh, const float* __restrict__ wih,
    _Float16* __restrict__ W1, _Float16* __restrict__ W2,
    float* __restrict__ bb, float* __restrict__ wx)
{
    const int idx = blockIdx.x * 256 + threadIdx.x;  // over Vd*Hd
    const int v = idx >> 9;
    const int k = idx & 511;
    const int j = v >> 2, q = v & 3;
    const int s = q * Hd + j;
    const float w = Wsrc[(size_t)s * Hd + k];
    const _Float16 w1 = (_Float16)w;
    W1[idx] = w1;
    W2[idx] = (_Float16)(w - (float)w1);
    if (k == 0) {
        bb[v] = bih[s] + bhh[s];
        wx[v] = wih[s];
    }
}

// One LSTM step via fp16x2-split MFMA.
// Grid 256 = bg(8)*32 + rg(32). Block: 64 gate-rows (16 j's) x 32 batches,
// 4 waves each 16 rows x 32 batches (2 col-tiles). K in 8 double-buffered
// 64-wide LDS tiles, chunk-XOR swizzled, staged with global_load_lds.
__global__ __launch_bounds__(256) void lstm_step(
    const _Float16* __restrict__ W1, const _Float16* __restrict__ W2, // [2048][512]
    const float* __restrict__ bb, const float* __restrict__ wx,       // [2048]
    const float* __restrict__ x, int t,                                // [B][T]
    const _Float16* __restrict__ h1i, const _Float16* __restrict__ h2i, // [B][H]
    _Float16* __restrict__ h1o, _Float16* __restrict__ h2o,
    float* __restrict__ c,                                             // [H][B]
    const float* __restrict__ linW, const float* __restrict__ linb,
    float* __restrict__ out, int is_dec)
{
    __shared__ alignas(16) _Float16 W1t[2][64 * 64];
    __shared__ alignas(16) _Float16 W2t[2][64 * 64];
    __shared__ alignas(16) _Float16 H1t[2][32 * 64];
    __shared__ alignas(16) _Float16 H2t[2][32 * 64];
    __shared__ _Float16 tr1[32][16];
    __shared__ _Float16 tr2[32][16];
    __shared__ float outp[4][32];

    const int tid = threadIdx.x;
    const int l   = tid & 63;
    const int wv  = tid >> 6;
    const int rg  = blockIdx.x & 31;
    const int bg  = blockIdx.x >> 5;
    const int v0  = rg * 64;
    const int b0  = bg * 32;

    // ---- staging (pre-swizzled global source, linear LDS dest) ----
    const int sr = l >> 3;       // row-within-8
    const int ss = l & 7;        // dest chunk
    const int sx = ss ^ sr;      // source k-chunk held at dest chunk ss
    const _Float16* pW1a = W1 + (size_t)(v0 + wv * 16 + sr) * Hd + sx * 8;
    const _Float16* pW1b = W1 + (size_t)(v0 + wv * 16 + 8 + sr) * Hd + sx * 8;
    const _Float16* pW2a = W2 + (size_t)(v0 + wv * 16 + sr) * Hd + sx * 8;
    const _Float16* pW2b = W2 + (size_t)(v0 + wv * 16 + 8 + sr) * Hd + sx * 8;
    const _Float16* pH1  = h1i + (size_t)(b0 + wv * 8 + sr) * Hd + sx * 8;
    const _Float16* pH2  = h2i + (size_t)(b0 + wv * 8 + sr) * Hd + sx * 8;

    // ---- fragment read offsets (half units) ----
    const int r16 = l & 15;
    const int g2  = l >> 4;
    const int key = r16 & 7;
    const int aro = (wv * 16 + r16) * 64;
    const int a0 = aro + ((g2    ) ^ key) * 8;
    const int a1 = aro + ((g2 + 4) ^ key) * 8;
    const int b00 = r16 * 64        + ((g2    ) ^ key) * 8;
    const int b01 = r16 * 64        + ((g2 + 4) ^ key) * 8;
    const int b10 = (16 + r16) * 64 + ((g2    ) ^ key) * 8;
    const int b11 = (16 + r16) * 64 + ((g2 + 4) ^ key) * 8;

    f32x4 acc0 = {0.f, 0.f, 0.f, 0.f};
    f32x4 acc1 = {0.f, 0.f, 0.f, 0.f};

    auto stage = [&](int buf, int kt) {
        const int ko = kt * 64;
        gl2lds16(pW1a + ko, &W1t[buf][(wv * 16) * 64]);
        gl2lds16(pW1b + ko, &W1t[buf][(wv * 16 + 8) * 64]);
        gl2lds16(pW2a + ko, &W2t[buf][(wv * 16) * 64]);
        gl2lds16(pW2b + ko, &W2t[buf][(wv * 16 + 8) * 64]);
        gl2lds16(pH1 + ko, &H1t[buf][(wv * 8) * 64]);
        gl2lds16(pH2 + ko, &H2t[buf][(wv * 8) * 64]);
    };
    auto rd = [&](const _Float16* base, int off) -> f16x8 {
        return *(const f16x8*)(base + off);
    };
    auto compute = [&](int buf) {
        {   // sub-step kk=0
            const f16x8 A1 = rd(&W1t[buf][0], a0), A2 = rd(&W2t[buf][0], a0);
            const f16x8 P0 = rd(&H1t[buf][0], b00), P1 = rd(&H1t[buf][0], b10);
            const f16x8 Q0 = rd(&H2t[buf][0], b00), Q1 = rd(&H2t[buf][0], b10);
            acc0 = __builtin_amdgcn_mfma_f32_16x16x32_f16(A1, P0, acc0, 0, 0, 0);
            acc1 = __builtin_amdgcn_mfma_f32_16x16x32_f16(A1, P1, acc1, 0, 0, 0);
            acc0 = __builtin_amdgcn_mfma_f32_16x16x32_f16(A1, Q0, acc0, 0, 0, 0);
            acc1 = __builtin_amdgcn_mfma_f32_16x16x32_f16(A1, Q1, acc1, 0, 0, 0);
            acc0 = __builtin_amdgcn_mfma_f32_16x16x32_f16(A2, P0, acc0, 0, 0, 0);
            acc1 = __builtin_amdgcn_mfma_f32_16x16x32_f16(A2, P1, acc1, 0, 0, 0);
        }
        {   // sub-step kk=1
            const f16x8 A1 = rd(&W1t[buf][0], a1), A2 = rd(&W2t[buf][0], a1);
            const f16x8 P0 = rd(&H1t[buf][0], b01), P1 = rd(&H1t[buf][0], b11);
            const f16x8 Q0 = rd(&H2t[buf][0], b01), Q1 = rd(&H2t[buf][0], b11);
            acc0 = __builtin_amdgcn_mfma_f32_16x16x32_f16(A1, P0, acc0, 0, 0, 0);
            acc1 = __builtin_amdgcn_mfma_f32_16x16x32_f16(A1, P1, acc1, 0, 0, 0);
            acc0 = __builtin_amdgcn_mfma_f32_16x16x32_f16(A1, Q0, acc0, 0, 0, 0);
            acc1 = __builtin_amdgcn_mfma_f32_16x16x32_f16(A1, Q1, acc1, 0, 0, 0);
            acc0 = __builtin_amdgcn_mfma_f32_16x16x32_f16(A2, P0, acc0, 0, 0, 0);
            acc1 = __builtin_amdgcn_mfma_f32_16x16x32_f16(A2, P1, acc1, 0, 0, 0);
        }
    };

    stage(0, 0);
    __syncthreads();
#pragma unroll
    for (int kt = 0; kt < 8; ++kt) {
        if (kt < 7) stage((kt + 1) & 1, kt + 1);
        compute(kt & 1);
        __syncthreads();
    }

    // ---- epilogue: lane owns hidden unit j, regs = (i,f,g,o) ----
    const int j = rg * 16 + wv * 4 + g2;
    const float4 bb4 = *(const float4*)(bb + 4 * j);
    const float4 wx4 = *(const float4*)(wx + 4 * j);
    const float lw = linW[j];

    float p[2];
#pragma unroll
    for (int ct = 0; ct < 2; ++ct) {
        const f32x4 a = ct ? acc1 : acc0;
        const int b = b0 + ct * 16 + r16;
        const float xb = x[(size_t)b * Td + t];
        const float gi = a[0] + bb4.x + xb * wx4.x;
        const float gf = a[1] + bb4.y + xb * wx4.y;
        const float gg = a[2] + bb4.z + xb * wx4.z;
        const float go = a[3] + bb4.w + xb * wx4.w;
        const size_t ci = (size_t)j * Bd + b;
        const float cn = sigm(gf) * c[ci] + sigm(gi) * tanh_fast(gg);
        c[ci] = cn;
        const float hn = sigm(go) * tanh_fast(cn);
        const _Float16 hh1 = (_Float16)hn;
        const _Float16 hh2 = (_Float16)(hn - (float)hh1);
        tr1[ct * 16 + r16][wv * 4 + g2] = hh1;
        tr2[ct * 16 + r16][wv * 4 + g2] = hh2;
        p[ct] = hn * lw;
    }
    __syncthreads();

    {   // coalesced h write: thread -> (batch bl, j-pair jp)
        const int bl = tid >> 3;
        const int jp = tid & 7;
        const size_t dst = (size_t)(b0 + bl) * Hd + rg * 16 + 2 * jp;
        union { _Float16 h[2]; uint32_t u; } pk;
        pk.h[0] = tr1[bl][2 * jp]; pk.h[1] = tr1[bl][2 * jp + 1];
        *(uint32_t*)(h1o + dst) = pk.u;
        pk.h[0] = tr2[bl][2 * jp]; pk.h[1] = tr2[bl][2 * jp + 1];
        *(uint32_t*)(h2o + dst) = pk.u;
    }

    if (is_dec) {
        float p0 = p[0], p1 = p[1];
        p0 += __shfl_xor(p0, 16); p0 += __shfl_xor(p0, 32);
        p1 += __shfl_xor(p1, 16); p1 += __shfl_xor(p1, 32);
        if (l < 16) { outp[wv][l] = p0; outp[wv][l + 16] = p1; }
        __syncthreads();
        if (tid < 32) {
            float s = outp[0][tid] + outp[1][tid] + outp[2][tid] + outp[3][tid];
            if (rg == 0) s += linb[0];
            atomicAdd(out + (size_t)(b0 + tid) * Td + t, s);
        }
    }
}

} // namespace

extern "C" void kernel_launch(void* const* d_in, const int* in_sizes, int n_in,
                              void* d_out, int out_size, void* d_ws, size_t ws_size,
                              hipStream_t stream) {
    (void)in_sizes; (void)n_in; (void)ws_size;
    const float* x    = (const float*)d_in[0];
    const float* eWih = (const float*)d_in[1];
    const float* eWhh = (const float*)d_in[2];
    const float* ebih = (const float*)d_in[3];
    const float* ebhh = (const float*)d_in[4];
    const float* dWih = (const float*)d_in[5];
    const float* dWhh = (const float*)d_in[6];
    const float* dbih = (const float*)d_in[7];
    const float* dbhh = (const float*)d_in[8];
    const float* linW = (const float*)d_in[9];
    const float* linb = (const float*)d_in[10];
    float* out = (float*)d_out;

    // workspace layout (~9.6 MB)
    _Float16* eW1 = (_Float16*)d_ws;
    _Float16* eW2 = eW1 + (size_t)Vd * Hd;
    _Float16* dW1 = eW2 + (size_t)Vd * Hd;
    _Float16* dW2 = dW1 + (size_t)Vd * Hd;
    float* ebb = (float*)(dW2 + (size_t)Vd * Hd);
    float* ewx = ebb + Vd;
    float* dbb = ewx + Vd;
    float* dwx = dbb + Vd;
    _Float16* h1A = (_Float16*)(dwx + Vd);
    _Float16* h2A = h1A + (size_t)Bd * Hd;
    _Float16* h1B = h2A + (size_t)Bd * Hd;
    _Float16* h2B = h1B + (size_t)Bd * Hd;
    float* c = (float*)(h2B + (size_t)Bd * Hd);

    hipMemsetAsync(h1A, 0, 2 * (size_t)Bd * Hd * sizeof(_Float16), stream);
    hipMemsetAsync(c, 0, (size_t)Hd * Bd * sizeof(float), stream);
    hipMemsetAsync(d_out, 0, (size_t)out_size * sizeof(float), stream);

    prep_weights<<<dim3(Vd * Hd / 256), dim3(256), 0, stream>>>(
        eWhh, ebih, ebhh, eWih, eW1, eW2, ebb, ewx);
    prep_weights<<<dim3(Vd * Hd / 256), dim3(256), 0, stream>>>(
        dWhh, dbih, dbhh, dWih, dW1, dW2, dbb, dwx);

    _Float16 *h1i = h1A, *h2i = h2A, *h1o = h1B, *h2o = h2B;
    dim3 grid(256), block(256);

    for (int t = 0; t < Td; ++t) {
        lstm_step<<<grid, block, 0, stream>>>(eW1, eW2, ebb, ewx, x, t,
                                              h1i, h2i, h1o, h2o, c,
                                              linW, linb, out, 0);
        _Float16* tmp;
        tmp = h1i; h1i = h1o; h1o = tmp;
        tmp = h2i; h2i = h2o; h2o = tmp;
    }

    hipMemsetAsync(c, 0, (size_t)Hd * Bd * sizeof(float), stream);

    for (int t = 0; t < Td; ++t) {
        lstm_step<<<grid, block, 0, stream>>>(dW1, dW2, dbb, dwx, x, t,
                                              h1i, h2i, h1o, h2o, c,
                                              linW, linb, out, 1);
        _Float16* tmp;
        tmp = h1i; h1i = h1o; h1o = tmp;
        tmp = h2i; h2i = h2o; h2o = tmp;
    }
}